// Round 18
// baseline (199.053 us; speedup 1.0000x reference)
//
#include <hip/hip_runtime.h>
#include <hip/hip_bf16.h>

#define N_NODES 20000
#define N_EDGES 320000
#define IN_DIM  1024
#define H_HEADS 8
#define C_CH    64
#define HC      512
#define LEAKY   0.2f
#define LN_EPS  1e-5f

// Extended columns: 0..511 = W_src, 512..519 = att_src fold, 520..527 =
// att_dst fold, 528..575 zero pad.
#define BCOLS 576
#define NCT   36            // 576/16 column tiles
#define NKT   32            // 1024/32 k tiles

// B is fragment-native tiled (R17, validated): wbtt[ct][kt][lane][8 bf16],
// one wave B-fragment = one coalesced 1KB load at tile base + lane*16B.

typedef short bf16x8 __attribute__((ext_vector_type(8)));
typedef float f32x4  __attribute__((ext_vector_type(4)));

__device__ __forceinline__ unsigned short f2bf(float f) {
    union { float f; unsigned int u; } c; c.f = f;
    unsigned int u = c.u;
    unsigned int r = (u + 0x7fffu + ((u >> 16) & 1u)) >> 16;   // RNE
    return (unsigned short)r;
}
__device__ __forceinline__ float bf2f(unsigned int h) {
    union { unsigned int u; float f; } c; c.u = h << 16; return c.f;
}
__device__ __forceinline__ unsigned int cvtpk(float lo, float hi) {
    unsigned int r;
    asm("v_cvt_pk_bf16_f32 %0, %1, %2" : "=v"(r) : "v"(lo), "v"(hi));
    return r;
}

// ---------------------------------------------------------------------------
// Pre pass: blocks [0,1250) deg histogram; [1250,1282) weight fold + retile.
#define DEG_BLOCKS 1250
#define PREP_BLOCKS NKT

__global__ __launch_bounds__(256) void pre_kernel(
        const int* __restrict__ ei,
        const float* __restrict__ Wsrc,
        const float* __restrict__ Wdst,
        const float* __restrict__ att_src,
        const float* __restrict__ att_dst,
        short* __restrict__ wbtt,
        int* __restrict__ deg) {
    __shared__ short sw[32 * 512];          // 32 KB bf16 Wsrc rows
    __shared__ float f1[32][8], f2[32][8];
    int t   = threadIdx.x;
    int bid = blockIdx.x;

    if (bid < DEG_BLOCKS) {                 // ---- deg histogram
        int e = bid * 256 + t;              // 1250*256 == N_EDGES
        atomicAdd(&deg[ei[N_EDGES + e]], 1);
        return;
    }

    // ---- weight fold + retile (one k-tile of 32 k's per block)
    int kt = bid - DEG_BLOCKS;              // 0..31
    int k0 = kt * 32;
    for (int i = t; i < 32 * 128; i += 256) {
        int kk = i >> 7, g4 = i & 127;
        float4 v = *(const float4*)(Wsrc + (size_t)(k0 + kk) * HC + g4 * 4);
        uint2 p;
        p.x = cvtpk(v.x, v.y);  p.y = cvtpk(v.z, v.w);
        *(uint2*)(&sw[kk * 512 + g4 * 4]) = p;
    }
    {
        int kk = t >> 3, h = t & 7;
        const float* wsr = Wsrc + (size_t)(k0 + kk) * HC + h * 64;
        const float* wdr = Wdst + (size_t)(k0 + kk) * HC + h * 64;
        const float* a1  = att_src + h * 64;
        const float* a2  = att_dst + h * 64;
        float s1 = 0.f, s2 = 0.f;
        #pragma unroll 8
        for (int c = 0; c < 64; ++c) {
            s1 += wsr[c] * a1[c];
            s2 += wdr[c] * a2[c];
        }
        f1[kk][h] = s1;  f2[kk][h] = s2;
    }
    __syncthreads();
    for (int idx = t; idx < NCT * 64; idx += 256) {
        int ct = idx >> 6, sl = idx & 63;
        int lr = sl & 15, lg = sl >> 4;
        int col = ct * 16 + lr;
        union { short v[8]; uint4 u; } pk;
        #pragma unroll
        for (int j = 0; j < 8; ++j) {
            int kk = lg * 8 + j;
            short val;
            if (col < 512)      val = sw[kk * 512 + col];
            else if (col < 520) val = (short)f2bf(f1[kk][col - 512]);
            else if (col < 528) val = (short)f2bf(f2[kk][col - 520]);
            else                val = 0;
            pk.v[j] = val;
        }
        *(uint4*)(wbtt + (((size_t)ct * 32 + kt) << 9) + sl * 8) = pk.u;
    }
}

// ---------------------------------------------------------------------------
// Standalone vectorized scan (R10): deg -> off, cursor.  1 block, 128 threads.
__global__ void scan_kernel(const int* __restrict__ deg,
                            int* __restrict__ off,
                            int* __restrict__ cursor) {
    __shared__ int wtot[2];
    int t = threadIdx.x;
    int lane = t & 63, w = t >> 6;
    const int4* deg4 = (const int4*)deg;
    int s = 0;
    if (t < 125) {                          // 125*160 == N_NODES
        #pragma unroll
        for (int j = 0; j < 40; ++j) {
            int4 u = deg4[t * 40 + j];
            s += u.x + u.y + u.z + u.w;
        }
    }
    int v = s;
    #pragma unroll
    for (int o = 1; o < 64; o <<= 1) {
        int u = __shfl_up(v, o);
        if (lane >= o) v += u;
    }
    if (lane == 63) wtot[w] = v;
    __syncthreads();
    int add = (w == 1) ? wtot[0] : 0;
    int run = add + v - s;
    if (t < 125) {
        int4* off4 = (int4*)off;
        int4* cur4 = (int4*)cursor;
        #pragma unroll
        for (int j = 0; j < 40; ++j) {
            int4 u = deg4[t * 40 + j];
            int4 o_;
            o_.x = run;
            o_.y = o_.x + u.x;
            o_.z = o_.y + u.y;
            o_.w = o_.z + u.z;
            off4[t * 40 + j] = o_;
            cur4[t * 40 + j] = o_;
            run = o_.w + u.w;
        }
        if (t == 124) off[N_NODES] = run;
    }
}

// ---------------------------------------------------------------------------
// A-PANEL-RESIDENT barrier-free MFMA GEMM.
// Block = 256 threads (4 waves), owns 32 rows (625 blocks = 20000 exactly).
// Phase 1 (once): stage the block's whole A panel 32x1024 into 64KB LDS —
//   fully coalesced fp32 reads (wave = 1KB contiguous), cvt_pk, XOR-swizzled
//   ds_write; ONE __syncthreads.
// Phase 2 (barrier-free): wave w owns col-tiles [w*9,(w+1)*9); streams 32
//   k-tiles: 2 swizzled ds_read_b128 A-fragments (2-way alias = free) +
//   9 coalesced 1KB fragment-native B loads (L2-resident) + 18 MFMA.
// A read from HBM exactly once (82 MB chip-wide).  B re-read per block but
// XCD-swizzled col-fastest order keeps it in each XCD's L2 (1.18 MB).
// LDS swizzle: slot(row, kc) = row*128 + (kc ^ (row&7))   [16B slots]
// Blocks [0,625): GEMM.  [625,1875): CSR edge scatter (needs cursor).
#define GEMM_BLKS 625
#define SCAT_BLKS 1250

__global__ __launch_bounds__(256) void gemm_scatter(
        const float* __restrict__ x,
        const short* __restrict__ wbtt,
        short* __restrict__ xsb,
        float* __restrict__ a_srcv,
        float* __restrict__ a_dstv,
        const int* __restrict__ ei,
        int* __restrict__ cursor,
        int* __restrict__ csr_src) {
    __shared__ short Apan[32 * 128 * 8];    // 64 KB
    int t = threadIdx.x;

    // ---- scatter blocks
    if (blockIdx.x >= GEMM_BLKS) {
        int e = (blockIdx.x - GEMM_BLKS) * 256 + t;   // 1250*256 == N_EDGES
        int d = ei[N_EDGES + e];
        int idx = atomicAdd(&cursor[d], 1);
        csr_src[idx] = ei[e];
        return;
    }

    // bijective XCD swizzle (m204) over 625 gemm blocks
    int orig = blockIdx.x;
    const int q = GEMM_BLKS >> 3, r = GEMM_BLKS & 7;
    int xcd  = orig & 7;
    int wgid = (xcd < r ? xcd * (q + 1) : r * (q + 1) + (xcd - r) * q) + (orig >> 3);
    int row0 = wgid * 32;

    int lane = t & 63;
    int w    = t >> 6;
    int lr   = lane & 15;
    int lg   = lane >> 4;

    // ---- phase 1: stage A panel (32 rows x 1024 fp32 -> bf16, swizzled)
    #pragma unroll 8
    for (int i = 0; i < 32; ++i) {
        int v   = t + 256 * i;              // 0..8191 float4 units
        int row = v >> 8;                   // 256 float4 per row
        int c   = v & 255;                  // fp32 16B-chunk index
        float4 f = *(const float4*)(x + (size_t)(row0 + row) * IN_DIM + c * 4);
        int slot = row * 128 + ((c >> 1) ^ (row & 7));
        uint2 p;
        p.x = cvtpk(f.x, f.y);  p.y = cvtpk(f.z, f.w);
        *(uint2*)(&Apan[slot * 8 + (c & 1) * 4]) = p;
    }
    __syncthreads();                        // the ONLY barrier

    // ---- phase 2: barrier-free MFMA stream
    int ct0 = w * 9;                        // wave's 9 col tiles
    const short* pb[9];
    #pragma unroll
    for (int ni = 0; ni < 9; ++ni)
        pb[ni] = wbtt + (((size_t)(ct0 + ni) * 32) << 9) + lane * 8;

    f32x4 acc[2][9] = {};

    #pragma unroll 2
    for (int kt = 0; kt < NKT; ++kt) {
        int kc  = kt * 4 + lg;
        int sA0 = (lr      ) * 128 + (kc ^ (lr & 7));
        int sA1 = (lr + 16 ) * 128 + (kc ^ (lr & 7));
        bf16x8 a0 = *(const bf16x8*)(&Apan[sA0 * 8]);
        bf16x8 a1 = *(const bf16x8*)(&Apan[sA1 * 8]);
        #pragma unroll
        for (int ni = 0; ni < 9; ++ni) {
            bf16x8 b = *(const bf16x8*)(pb[ni] + kt * 512);
            acc[0][ni] = __builtin_amdgcn_mfma_f32_16x16x32_bf16(a0, b, acc[0][ni], 0, 0, 0);
            acc[1][ni] = __builtin_amdgcn_mfma_f32_16x16x32_bf16(a1, b, acc[1][ni], 0, 0, 0);
        }
    }

    // epilogue: C/D layout col=lane&15, row=(lane>>4)*4+reg
    #pragma unroll
    for (int mi = 0; mi < 2; ++mi) {
        #pragma unroll
        for (int rr = 0; rr < 4; ++rr) {
            int row = row0 + mi * 16 + lg * 4 + rr;
            #pragma unroll
            for (int ni = 0; ni < 9; ++ni) {
                int col = (ct0 + ni) * 16 + lr;
                float v = acc[mi][ni][rr];
                if (col < 512)      xsb[(size_t)row * HC + col] = (short)f2bf(v);
                else if (col < 520) a_srcv[(size_t)row * 8 + (col - 512)] = v;
                else if (col < 528) a_dstv[(size_t)row * 8 + (col - 520)] = v;
            }
        }
    }
}

// ---------------------------------------------------------------------------
// ONE WAVE per destination node (4 independent waves/block, no barriers).
__global__ __launch_bounds__(256) void aggregate_ln(
        const int* __restrict__ off,
        const int* __restrict__ csr_src,
        const float* __restrict__ a_srcv,
        const float* __restrict__ a_dstv,
        const short* __restrict__ xsb,
        const float* __restrict__ bias,
        const float* __restrict__ gamma,
        const float* __restrict__ beta,
        const float* __restrict__ prelu_a,
        float* __restrict__ out) {
    int lane = threadIdx.x & 63;
    int n    = blockIdx.x * 4 + (threadIdx.x >> 6);   // 5000 x 4 waves = 20000
    int ch0  = lane * 8;
    int h    = lane >> 3;

    int start = off[n], end = off[n + 1];
    float ad  = a_dstv[(size_t)n * 8 + h];

    float acc[8] = {};
    float wsum = 0.f;

    int i = start;
    for (; i + 1 < end; i += 2) {
        int s0 = __builtin_amdgcn_readfirstlane(csr_src[i]);
        int s1 = __builtin_amdgcn_readfirstlane(csr_src[i + 1]);
        float sc0 = a_srcv[(size_t)s0 * 8 + h] + ad;
        float sc1 = a_srcv[(size_t)s1 * 8 + h] + ad;
        uint4 u0 = *(const uint4*)(xsb + (size_t)s0 * HC + ch0);
        uint4 u1 = *(const uint4*)(xsb + (size_t)s1 * HC + ch0);
        sc0 = (sc0 >= 0.f) ? sc0 : LEAKY * sc0;
        sc1 = (sc1 >= 0.f) ? sc1 : LEAKY * sc1;
        float w0 = __expf(sc0);
        float w1 = __expf(sc1);
        acc[0] = fmaf(w0, bf2f(u0.x & 0xffffu), acc[0]);
        acc[1] = fmaf(w0, bf2f(u0.x >> 16),     acc[1]);
        acc[2] = fmaf(w0, bf2f(u0.y & 0xffffu), acc[2]);
        acc[3] = fmaf(w0, bf2f(u0.y >> 16),     acc[3]);
        acc[4] = fmaf(w0, bf2f(u0.z & 0xffffu), acc[4]);
        acc[5] = fmaf(w0, bf2f(u0.z >> 16),     acc[5]);
        acc[6] = fmaf(w0, bf2f(u0.w & 0xffffu), acc[6]);
        acc[7] = fmaf(w0, bf2f(u0.w >> 16),     acc[7]);
        acc[0] = fmaf(w1, bf2f(u1.x & 0xffffu), acc[0]);
        acc[1] = fmaf(w1, bf2f(u1.x >> 16),     acc[1]);
        acc[2] = fmaf(w1, bf2f(u1.y & 0xffffu), acc[2]);
        acc[3] = fmaf(w1, bf2f(u1.y >> 16),     acc[3]);
        acc[4] = fmaf(w1, bf2f(u1.z & 0xffffu), acc[4]);
        acc[5] = fmaf(w1, bf2f(u1.z >> 16),     acc[5]);
        acc[6] = fmaf(w1, bf2f(u1.w & 0xffffu), acc[6]);
        acc[7] = fmaf(w1, bf2f(u1.w >> 16),     acc[7]);
        wsum += w0 + w1;
    }
    if (i < end) {
        int s0 = __builtin_amdgcn_readfirstlane(csr_src[i]);
        float sc0 = a_srcv[(size_t)s0 * 8 + h] + ad;
        uint4 u0 = *(const uint4*)(xsb + (size_t)s0 * HC + ch0);
        sc0 = (sc0 >= 0.f) ? sc0 : LEAKY * sc0;
        float w0 = __expf(sc0);
        acc[0] = fmaf(w0, bf2f(u0.x & 0xffffu), acc[0]);
        acc[1] = fmaf(w0, bf2f(u0.x >> 16),     acc[1]);
        acc[2] = fmaf(w0, bf2f(u0.y & 0xffffu), acc[2]);
        acc[3] = fmaf(w0, bf2f(u0.y >> 16),     acc[3]);
        acc[4] = fmaf(w0, bf2f(u0.z & 0xffffu), acc[4]);
        acc[5] = fmaf(w0, bf2f(u0.z >> 16),     acc[5]);
        acc[6] = fmaf(w0, bf2f(u0.w & 0xffffu), acc[6]);
        acc[7] = fmaf(w0, bf2f(u0.w >> 16),     acc[7]);
        wsum += w0;
    }

    float inv = 1.f / (wsum + 1e-16f);
    float4 b0 = *(const float4*)(bias + ch0);
    float4 b1 = *(const float4*)(bias + ch0 + 4);
    float v8[8];
    float psum = 0.f, psq = 0.f;
    const float bb[8] = {b0.x, b0.y, b0.z, b0.w, b1.x, b1.y, b1.z, b1.w};
    #pragma unroll
    for (int j = 0; j < 8; ++j) {
        v8[j] = acc[j] * inv + bb[j];
        psum += v8[j];
        psq  += v8[j] * v8[j];
    }
    #pragma unroll
    for (int o = 32; o > 0; o >>= 1) {
        psum += __shfl_xor(psum, o);
        psq  += __shfl_xor(psq, o);
    }
    float mu   = psum * (1.f / (float)HC);
    float var  = psq * (1.f / (float)HC) - mu * mu;
    float rstd = rsqrtf(var + LN_EPS);

    float4 g0 = *(const float4*)(gamma + ch0);
    float4 g1 = *(const float4*)(gamma + ch0 + 4);
    float4 e0 = *(const float4*)(beta + ch0);
    float4 e1 = *(const float4*)(beta + ch0 + 4);
    float4 p0 = *(const float4*)(prelu_a + ch0);
    float4 p1 = *(const float4*)(prelu_a + ch0 + 4);
    const float gg[8] = {g0.x, g0.y, g0.z, g0.w, g1.x, g1.y, g1.z, g1.w};
    const float ee[8] = {e0.x, e0.y, e0.z, e0.w, e1.x, e1.y, e1.z, e1.w};
    const float pp[8] = {p0.x, p0.y, p0.z, p0.w, p1.x, p1.y, p1.z, p1.w};
    float y[8];
    #pragma unroll
    for (int j = 0; j < 8; ++j) {
        float v = (v8[j] - mu) * rstd * gg[j] + ee[j];
        y[j] = (v >= 0.f) ? v : pp[j] * v;
    }
    float4* o4 = (float4*)(out + (size_t)n * HC + ch0);
    o4[0] = make_float4(y[0], y[1], y[2], y[3]);
    o4[1] = make_float4(y[4], y[5], y[6], y[7]);
}

// ---------------------------------------------------------------------------
extern "C" void kernel_launch(void* const* d_in, const int* in_sizes, int n_in,
                              void* d_out, int out_size, void* d_ws, size_t ws_size,
                              hipStream_t stream) {
    const float* x        = (const float*)d_in[0];
    const int*   ei       = (const int*)d_in[2];
    const float* Wsrc     = (const float*)d_in[4];
    const float* Wdst     = (const float*)d_in[5];
    const float* att_src  = (const float*)d_in[6];
    const float* att_dst  = (const float*)d_in[7];
    const float* bias     = (const float*)d_in[8];
    const float* gamma    = (const float*)d_in[9];
    const float* beta     = (const float*)d_in[10];
    const float* prelu_a  = (const float*)d_in[11];
    float* out            = (float*)d_out;

    char*  ws = (char*)d_ws;
    size_t o  = 0;
    auto alloc = [&](size_t bytes) -> void* {
        void* p = ws + o;
        o += (bytes + 255) & ~(size_t)255;
        return p;
    };
    short* wbtt    = (short*)alloc(sizeof(short) * NCT * NKT * 512);       // 1.18 MB
    short* xsb     = (short*)alloc(sizeof(short) * (size_t)N_NODES * HC);  // 20.5 MB
    float* a_srcv  = (float*)alloc(sizeof(float) * N_NODES * 8);
    float* a_dstv  = (float*)alloc(sizeof(float) * N_NODES * 8);
    int*   deg     = (int*)alloc(sizeof(int) * N_NODES);
    int*   off     = (int*)alloc(sizeof(int) * (N_NODES + 1));
    int*   cursor  = (int*)alloc(sizeof(int) * N_NODES);
    int*   csr_src = (int*)alloc(sizeof(int) * N_EDGES);                   // 1.28 MB

    hipMemsetAsync(deg, 0, sizeof(int) * N_NODES, stream);

    pre_kernel<<<DEG_BLOCKS + PREP_BLOCKS, 256, 0, stream>>>(
        ei, Wsrc, Wdst, att_src, att_dst, wbtt, deg);

    scan_kernel<<<1, 128, 0, stream>>>(deg, off, cursor);

    gemm_scatter<<<GEMM_BLKS + SCAT_BLKS, 256, 0, stream>>>(
        x, wbtt, xsb, a_srcv, a_dstv, ei, cursor, csr_src);

    aggregate_ln<<<N_NODES / 4, 256, 0, stream>>>(
        off, csr_src, a_srcv, a_dstv, xsb, bias, gamma, beta, prelu_a, out);
}

// Round 19
// 156.061 us; speedup vs baseline: 1.2755x; 1.2755x over previous
//
#include <hip/hip_runtime.h>
#include <hip/hip_bf16.h>

#define N_NODES 20000
#define N_EDGES 320000
#define IN_DIM  1024
#define H_HEADS 8
#define C_CH    64
#define HC      512
#define LEAKY   0.2f
#define LN_EPS  1e-5f

// Extended (transposed) weight: rows 0..511 = W_src cols, 512..519 = att_src fold,
// 520..527 = att_dst fold, 528..575 zero pad.  wbT[col][k], bf16.
#define BCOLS 576

typedef short bf16x8 __attribute__((ext_vector_type(8)));
typedef float f32x4  __attribute__((ext_vector_type(4)));

__device__ __forceinline__ unsigned short f2bf(float f) {
    union { float f; unsigned int u; } c; c.f = f;
    unsigned int u = c.u;
    unsigned int r = (u + 0x7fffu + ((u >> 16) & 1u)) >> 16;   // RNE
    return (unsigned short)r;
}
__device__ __forceinline__ float bf2f(unsigned int h) {
    union { unsigned int u; float f; } c; c.u = h << 16; return c.f;
}
__device__ __forceinline__ void gload_lds16(const void* g, void* l) {
    __builtin_amdgcn_global_load_lds(
        (const __attribute__((address_space(1))) unsigned int*)g,
        (__attribute__((address_space(3))) unsigned int*)l, 16, 0, 0);
}

// ---------------------------------------------------------------------------
// STANDALONE x fp32 -> xb bf16 (xb lives in d_out).  Kept separate from the
// deg atomics: co-dispatching them (R12) made the combined kernel 55 us —
// the stream evicts deg's hot L2 lines, serializing every atomic on HBM.
__global__ __launch_bounds__(256) void convert_x(const float* __restrict__ x,
                                                 short* __restrict__ xb) {
    const int total = N_NODES * IN_DIM / 8;
    int stride = gridDim.x * blockDim.x;
    for (int i = blockIdx.x * blockDim.x + threadIdx.x; i < total; i += stride) {
        float4 a = ((const float4*)x)[(size_t)i * 2];
        float4 b = ((const float4*)x)[(size_t)i * 2 + 1];
        uint4 r;
        r.x = (unsigned int)f2bf(a.x) | ((unsigned int)f2bf(a.y) << 16);
        r.y = (unsigned int)f2bf(a.z) | ((unsigned int)f2bf(a.w) << 16);
        r.z = (unsigned int)f2bf(b.x) | ((unsigned int)f2bf(b.y) << 16);
        r.w = (unsigned int)f2bf(b.z) | ((unsigned int)f2bf(b.w) << 16);
        *(uint4*)(&xb[(size_t)i * 8]) = r;
    }
}

// ---------------------------------------------------------------------------
#define DEG_BLOCKS 1250

__global__ __launch_bounds__(256) void deg_hist(
        const int* __restrict__ ei, int* __restrict__ deg) {
    int e = blockIdx.x * 256 + threadIdx.x;           // 1250*256 == N_EDGES
    atomicAdd(&deg[ei[N_EDGES + e]], 1);
}

// ---------------------------------------------------------------------------
// Build wbT (bf16, [BCOLS][IN_DIM]).  grid = 1024 prep blocks + 1 scan tail
// block.  Scan is vectorized: 125 threads x 160 elements (40 x int4).
__global__ void prep_w_scan(const float* __restrict__ Wsrc,
                            const float* __restrict__ Wdst,
                            const float* __restrict__ att_src,
                            const float* __restrict__ att_dst,
                            short* __restrict__ wbT,
                            const int* __restrict__ deg,
                            int* __restrict__ off,
                            int* __restrict__ cursor) {
    int t = threadIdx.x;                  // block = 128 threads

    if (blockIdx.x == IN_DIM) {           // ---- scan tail block
        __shared__ int wtot[2];
        int lane = t & 63, w = t >> 6;
        const int4* deg4 = (const int4*)deg;
        int s = 0;
        if (t < 125) {                    // 125*160 == N_NODES exactly
            #pragma unroll
            for (int j = 0; j < 40; ++j) {
                int4 u = deg4[t * 40 + j];
                s += u.x + u.y + u.z + u.w;
            }
        }
        int v = s;
        #pragma unroll
        for (int o = 1; o < 64; o <<= 1) {
            int u = __shfl_up(v, o);
            if (lane >= o) v += u;
        }
        if (lane == 63) wtot[w] = v;
        __syncthreads();
        int add = (w == 1) ? wtot[0] : 0;
        int run = add + v - s;            // exclusive prefix of this segment
        if (t < 125) {
            int4* off4 = (int4*)off;
            int4* cur4 = (int4*)cursor;
            #pragma unroll
            for (int j = 0; j < 40; ++j) {
                int4 u = deg4[t * 40 + j];
                int4 o_;
                o_.x = run;
                o_.y = o_.x + u.x;
                o_.z = o_.y + u.y;
                o_.w = o_.z + u.z;
                off4[t * 40 + j] = o_;
                cur4[t * 40 + j] = o_;
                run = o_.w + u.w;
            }
            if (t == 124) off[N_NODES] = run;
        }
        return;
    }

    int k = blockIdx.x;
    float4 v = *(const float4*)(Wsrc + (size_t)k * HC + t * 4);
    wbT[(size_t)(t * 4 + 0) * IN_DIM + k] = (short)f2bf(v.x);
    wbT[(size_t)(t * 4 + 1) * IN_DIM + k] = (short)f2bf(v.y);
    wbT[(size_t)(t * 4 + 2) * IN_DIM + k] = (short)f2bf(v.z);
    wbT[(size_t)(t * 4 + 3) * IN_DIM + k] = (short)f2bf(v.w);
    if (t < 16) {
        int h = t & 7;
        const float* W   = (t < 8) ? Wsrc : Wdst;
        const float* att = (t < 8) ? att_src : att_dst;
        float s = 0.f;
        #pragma unroll
        for (int c = 0; c < C_CH; ++c)
            s += W[(size_t)k * HC + h * C_CH + c] * att[h * C_CH + c];
        wbT[(size_t)(512 + t) * IN_DIM + k] = (short)f2bf(s);
    } else if (t < 64) {
        wbT[(size_t)(512 + t) * IN_DIM + k] = 0;   // pad cols 528..575
    }
}

// ---------------------------------------------------------------------------
// MFMA GEMM (R12 verbatim — the best-measured gemm, <55 us): small-tile
// high-TLP BM=64 x BN=96 x BK=64, 4 waves (2x2), single 20 KB LDS buffer,
// coalesced staging + XOR swizzle, 1878 GEMM blocks (7.3/CU) + 1250 fused
// CSR-scatter blocks.
#define BM 64
#define BN 96
#define BK 64
#define NCOLT (BCOLS / BN)                  // 6
#define NROWT ((N_NODES + BM - 1) / BM)     // 313
#define NWG (NCOLT * NROWT)                 // 1878
#define KSTEPS (IN_DIM / BK)                // 16
#define A_SLOTS (BM * BK / 8)               // 512 x 16B = 8 KB
#define B_SLOTS (BN * BK / 8)               // 768 x 16B = 12 KB

__global__ __launch_bounds__(256) void gemm_scatter(
        const short* __restrict__ xb,
        const short* __restrict__ wbT,
        short* __restrict__ xsb,
        float* __restrict__ a_srcv,
        float* __restrict__ a_dstv,
        const int* __restrict__ ei,
        int* __restrict__ cursor,
        int* __restrict__ csr_src) {
    __shared__ short As[A_SLOTS * 8];       // 8 KB
    __shared__ short Bs[B_SLOTS * 8];       // 12 KB  (20 KB total)

    int t = threadIdx.x;

    // ---- scatter blocks: bare CSR scatter, sorted by dst
    if (blockIdx.x >= NWG) {
        int e = (blockIdx.x - NWG) * 256 + t;   // 1250*256 == N_EDGES exactly
        int d = ei[N_EDGES + e];
        int idx = atomicAdd(&cursor[d], 1);
        csr_src[idx] = ei[e];
        return;
    }

    // bijective XCD swizzle (m204): contiguous chunk of wgids per XCD
    int orig = blockIdx.x;
    const int q = NWG >> 3, r = NWG & 7;
    int xcd  = orig & 7;
    int wgid = (xcd < r ? xcd * (q + 1) : r * (q + 1) + (xcd - r) * q) + (orig >> 3);
    int col0 = (wgid % NCOLT) * BN;         // col tiles fastest -> A rows L2-local
    int row0 = (wgid / NCOLT) * BM;

    int lane = t & 63;
    int w    = t >> 6;
    int lr   = lane & 15;
    int lg   = lane >> 4;                   // k-group 0..3
    int sw   = lr & 7;                      // fragment-read swizzle key
    int wr   = (w >> 1) * 32;               // wave row offset (2x2 waves)
    int wc   = (w & 1) * 48;                // wave col offset

    // staging source pointers: A 2 slots/thread, B 3 slots/thread.
    // slot s: m = s>>3, kcp = s&7; source k-chunk kc = kcp ^ (m&7).
    const short* a_base[2];
    #pragma unroll
    for (int i = 0; i < 2; ++i) {
        int s  = t + 256 * i;               // 0..511
        int m  = s >> 3;
        int kc = (s & 7) ^ (m & 7);
        int gm = row0 + m;
        if (gm >= N_NODES) gm = N_NODES - 1;   // clamp (dead rows, in-bounds)
        a_base[i] = xb + (size_t)gm * IN_DIM + kc * 8;
    }
    const short* b_base[3];
    #pragma unroll
    for (int i = 0; i < 3; ++i) {
        int s  = t + 256 * i;               // 0..767
        int c  = s >> 3;
        int kc = (s & 7) ^ (c & 7);
        b_base[i] = wbT + (size_t)(col0 + c) * IN_DIM + kc * 8;
    }

    f32x4 acc[2][3] = {};

    for (int step = 0; step < KSTEPS; ++step) {
        int k0 = step * BK;
        #pragma unroll
        for (int i = 0; i < 2; ++i)
            gload_lds16(a_base[i] + k0, &As[(t + 256 * i) * 8]);
        #pragma unroll
        for (int i = 0; i < 3; ++i)
            gload_lds16(b_base[i] + k0, &Bs[(t + 256 * i) * 8]);
        asm volatile("s_waitcnt vmcnt(0)" ::: "memory");
        __builtin_amdgcn_s_barrier();

        #pragma unroll
        for (int ks = 0; ks < 2; ++ks) {
            int kc  = ks * 4 + lg;
            int kca = kc ^ sw;              // swizzled chunk index
            bf16x8 af[2], bfr[3];
            #pragma unroll
            for (int mi = 0; mi < 2; ++mi)
                af[mi] = *(const bf16x8*)(&As[((wr + mi * 16 + lr) * 8 + kca) * 8]);
            #pragma unroll
            for (int ni = 0; ni < 3; ++ni)
                bfr[ni] = *(const bf16x8*)(&Bs[((wc + ni * 16 + lr) * 8 + kca) * 8]);
            __builtin_amdgcn_s_setprio(1);
            #pragma unroll
            for (int mi = 0; mi < 2; ++mi)
                #pragma unroll
                for (int ni = 0; ni < 3; ++ni)
                    acc[mi][ni] = __builtin_amdgcn_mfma_f32_16x16x32_bf16(
                        af[mi], bfr[ni], acc[mi][ni], 0, 0, 0);
            __builtin_amdgcn_s_setprio(0);
        }
        __builtin_amdgcn_s_barrier();       // reads done before next overwrite
    }

    // epilogue: C/D layout col=lane&15, row=(lane>>4)*4+reg
    #pragma unroll
    for (int mi = 0; mi < 2; ++mi) {
        #pragma unroll
        for (int rr = 0; rr < 4; ++rr) {
            int row = row0 + wr + mi * 16 + lg * 4 + rr;
            if (row >= N_NODES) continue;
            #pragma unroll
            for (int ni = 0; ni < 3; ++ni) {
                int col = col0 + wc + ni * 16 + lr;
                float v = acc[mi][ni][rr];
                if (col < 512)      xsb[(size_t)row * HC + col] = (short)f2bf(v);
                else if (col < 520) a_srcv[(size_t)row * 8 + (col - 512)] = v;
                else if (col < 528) a_dstv[(size_t)row * 8 + (col - 520)] = v;
            }
        }
    }
}

// ---------------------------------------------------------------------------
// ONE WAVE per destination node (4 independent waves/block, no barriers).
// Lane owns 8 channels of one head: per edge, one dwordx4 gather per lane,
// one weight compute, 8 FMAs.  LN via 6-step shfl_xor across the wave.
__global__ __launch_bounds__(256) void aggregate_ln(
        const int* __restrict__ off,
        const int* __restrict__ csr_src,
        const float* __restrict__ a_srcv,
        const float* __restrict__ a_dstv,
        const short* __restrict__ xsb,
        const float* __restrict__ bias,
        const float* __restrict__ gamma,
        const float* __restrict__ beta,
        const float* __restrict__ prelu_a,
        float* __restrict__ out) {
    int lane = threadIdx.x & 63;
    int n    = blockIdx.x * 4 + (threadIdx.x >> 6);   // grid 5000 x 4 waves = 20000
    int ch0  = lane * 8;
    int h    = lane >> 3;

    int start = off[n], end = off[n + 1];
    float ad  = a_dstv[(size_t)n * 8 + h];

    float acc[8] = {};
    float wsum = 0.f;

    int i = start;
    for (; i + 1 < end; i += 2) {
        int s0 = __builtin_amdgcn_readfirstlane(csr_src[i]);
        int s1 = __builtin_amdgcn_readfirstlane(csr_src[i + 1]);
        float sc0 = a_srcv[(size_t)s0 * 8 + h] + ad;
        float sc1 = a_srcv[(size_t)s1 * 8 + h] + ad;
        uint4 u0 = *(const uint4*)(xsb + (size_t)s0 * HC + ch0);
        uint4 u1 = *(const uint4*)(xsb + (size_t)s1 * HC + ch0);
        sc0 = (sc0 >= 0.f) ? sc0 : LEAKY * sc0;
        sc1 = (sc1 >= 0.f) ? sc1 : LEAKY * sc1;
        float w0 = __expf(sc0);
        float w1 = __expf(sc1);
        acc[0] = fmaf(w0, bf2f(u0.x & 0xffffu), acc[0]);
        acc[1] = fmaf(w0, bf2f(u0.x >> 16),     acc[1]);
        acc[2] = fmaf(w0, bf2f(u0.y & 0xffffu), acc[2]);
        acc[3] = fmaf(w0, bf2f(u0.y >> 16),     acc[3]);
        acc[4] = fmaf(w0, bf2f(u0.z & 0xffffu), acc[4]);
        acc[5] = fmaf(w0, bf2f(u0.z >> 16),     acc[5]);
        acc[6] = fmaf(w0, bf2f(u0.w & 0xffffu), acc[6]);
        acc[7] = fmaf(w0, bf2f(u0.w >> 16),     acc[7]);
        acc[0] = fmaf(w1, bf2f(u1.x & 0xffffu), acc[0]);
        acc[1] = fmaf(w1, bf2f(u1.x >> 16),     acc[1]);
        acc[2] = fmaf(w1, bf2f(u1.y & 0xffffu), acc[2]);
        acc[3] = fmaf(w1, bf2f(u1.y >> 16),     acc[3]);
        acc[4] = fmaf(w1, bf2f(u1.z & 0xffffu), acc[4]);
        acc[5] = fmaf(w1, bf2f(u1.z >> 16),     acc[5]);
        acc[6] = fmaf(w1, bf2f(u1.w & 0xffffu), acc[6]);
        acc[7] = fmaf(w1, bf2f(u1.w >> 16),     acc[7]);
        wsum += w0 + w1;
    }
    if (i < end) {
        int s0 = __builtin_amdgcn_readfirstlane(csr_src[i]);
        float sc0 = a_srcv[(size_t)s0 * 8 + h] + ad;
        uint4 u0 = *(const uint4*)(xsb + (size_t)s0 * HC + ch0);
        sc0 = (sc0 >= 0.f) ? sc0 : LEAKY * sc0;
        float w0 = __expf(sc0);
        acc[0] = fmaf(w0, bf2f(u0.x & 0xffffu), acc[0]);
        acc[1] = fmaf(w0, bf2f(u0.x >> 16),     acc[1]);
        acc[2] = fmaf(w0, bf2f(u0.y & 0xffffu), acc[2]);
        acc[3] = fmaf(w0, bf2f(u0.y >> 16),     acc[3]);
        acc[4] = fmaf(w0, bf2f(u0.z & 0xffffu), acc[4]);
        acc[5] = fmaf(w0, bf2f(u0.z >> 16),     acc[5]);
        acc[6] = fmaf(w0, bf2f(u0.w & 0xffffu), acc[6]);
        acc[7] = fmaf(w0, bf2f(u0.w >> 16),     acc[7]);
        wsum += w0;
    }

    float inv = 1.f / (wsum + 1e-16f);
    float4 b0 = *(const float4*)(bias + ch0);
    float4 b1 = *(const float4*)(bias + ch0 + 4);
    float v8[8];
    float psum = 0.f, psq = 0.f;
    const float bb[8] = {b0.x, b0.y, b0.z, b0.w, b1.x, b1.y, b1.z, b1.w};
    #pragma unroll
    for (int j = 0; j < 8; ++j) {
        v8[j] = acc[j] * inv + bb[j];
        psum += v8[j];
        psq  += v8[j] * v8[j];
    }
    #pragma unroll
    for (int o = 32; o > 0; o >>= 1) {
        psum += __shfl_xor(psum, o);
        psq  += __shfl_xor(psq, o);
    }
    float mu   = psum * (1.f / (float)HC);
    float var  = psq * (1.f / (float)HC) - mu * mu;
    float rstd = rsqrtf(var + LN_EPS);

    float4 g0 = *(const float4*)(gamma + ch0);
    float4 g1 = *(const float4*)(gamma + ch0 + 4);
    float4 e0 = *(const float4*)(beta + ch0);
    float4 e1 = *(const float4*)(beta + ch0 + 4);
    float4 p0 = *(const float4*)(prelu_a + ch0);
    float4 p1 = *(const float4*)(prelu_a + ch0 + 4);
    const float gg[8] = {g0.x, g0.y, g0.z, g0.w, g1.x, g1.y, g1.z, g1.w};
    const float ee[8] = {e0.x, e0.y, e0.z, e0.w, e1.x, e1.y, e1.z, e1.w};
    const float pp[8] = {p0.x, p0.y, p0.z, p0.w, p1.x, p1.y, p1.z, p1.w};
    float y[8];
    #pragma unroll
    for (int j = 0; j < 8; ++j) {
        float v = (v8[j] - mu) * rstd * gg[j] + ee[j];
        y[j] = (v >= 0.f) ? v : pp[j] * v;
    }
    float4* o4 = (float4*)(out + (size_t)n * HC + ch0);
    o4[0] = make_float4(y[0], y[1], y[2], y[3]);
    o4[1] = make_float4(y[4], y[5], y[6], y[7]);
}

// ---------------------------------------------------------------------------
extern "C" void kernel_launch(void* const* d_in, const int* in_sizes, int n_in,
                              void* d_out, int out_size, void* d_ws, size_t ws_size,
                              hipStream_t stream) {
    const float* x        = (const float*)d_in[0];
    const int*   ei       = (const int*)d_in[2];
    const float* Wsrc     = (const float*)d_in[4];
    const float* Wdst     = (const float*)d_in[5];
    const float* att_src  = (const float*)d_in[6];
    const float* att_dst  = (const float*)d_in[7];
    const float* bias     = (const float*)d_in[8];
    const float* gamma    = (const float*)d_in[9];
    const float* beta     = (const float*)d_in[10];
    const float* prelu_a  = (const float*)d_in[11];
    float* out            = (float*)d_out;

    char*  ws = (char*)d_ws;
    size_t o  = 0;
    auto alloc = [&](size_t bytes) -> void* {
        void* p = ws + o;
        o += (bytes + 255) & ~(size_t)255;
        return p;
    };
    short* wbT     = (short*)alloc(sizeof(short) * BCOLS * IN_DIM);        // 1.18 MB
    short* xsb     = (short*)alloc(sizeof(short) * (size_t)N_NODES * HC);  // 20.5 MB
    float* a_srcv  = (float*)alloc(sizeof(float) * N_NODES * 8);
    float* a_dstv  = (float*)alloc(sizeof(float) * N_NODES * 8);
    int*   deg     = (int*)alloc(sizeof(int) * N_NODES);
    int*   off     = (int*)alloc(sizeof(int) * (N_NODES + 1));
    int*   cursor  = (int*)alloc(sizeof(int) * N_NODES);
    int*   csr_src = (int*)alloc(sizeof(int) * N_EDGES);                   // 1.28 MB

    // xb (bf16 x) lives in d_out: exactly N*1024*2B = N*512*4B; d_out is dead
    // until aggregate_ln fully overwrites it.
    short* xb = (short*)d_out;

    hipMemsetAsync(deg, 0, sizeof(int) * N_NODES, stream);

    deg_hist<<<DEG_BLOCKS, 256, 0, stream>>>(ei, deg);

    convert_x<<<2048, 256, 0, stream>>>(x, xb);

    // 1024 prep blocks + 1 scan tail block (scan needs deg from deg_hist)
    prep_w_scan<<<IN_DIM + 1, 128, 0, stream>>>(Wsrc, Wdst, att_src, att_dst,
                                                wbT, deg, off, cursor);

    // GEMM blocks + fused edge_scatter blocks (scatter needs cursor from scan)
    gemm_scatter<<<NWG + DEG_BLOCKS, 256, 0, stream>>>(
        xb, wbT, xsb, a_srcv, a_dstv, ei, cursor, csr_src);

    aggregate_ln<<<N_NODES / 4, 256, 0, stream>>>(
        off, csr_src, a_srcv, a_dstv, xsb, bias, gamma, beta, prelu_a, out);
}

// Round 20
// 152.865 us; speedup vs baseline: 1.3021x; 1.0209x over previous
//
#include <hip/hip_runtime.h>
#include <hip/hip_bf16.h>

#define N_NODES 20000
#define N_EDGES 320000
#define IN_DIM  1024
#define H_HEADS 8
#define C_CH    64
#define HC      512
#define LEAKY   0.2f
#define LN_EPS  1e-5f

// Extended (transposed) weight: rows 0..511 = W_src cols, 512..519 = att_src fold,
// 520..527 = att_dst fold, 528..575 zero pad.  wbT[col][k], bf16.
#define BCOLS 576

typedef short bf16x8 __attribute__((ext_vector_type(8)));
typedef float f32x4  __attribute__((ext_vector_type(4)));

__device__ __forceinline__ unsigned short f2bf(float f) {
    union { float f; unsigned int u; } c; c.f = f;
    unsigned int u = c.u;
    unsigned int r = (u + 0x7fffu + ((u >> 16) & 1u)) >> 16;   // RNE
    return (unsigned short)r;
}
__device__ __forceinline__ float bf2f(unsigned int h) {
    union { unsigned int u; float f; } c; c.u = h << 16; return c.f;
}
__device__ __forceinline__ void gload_lds16(const void* g, void* l) {
    __builtin_amdgcn_global_load_lds(
        (const __attribute__((address_space(1))) unsigned int*)g,
        (__attribute__((address_space(3))) unsigned int*)l, 16, 0, 0);
}

// ---------------------------------------------------------------------------
#define DEG_BLOCKS 1250

__global__ __launch_bounds__(256) void deg_hist(
        const int* __restrict__ ei, int* __restrict__ deg) {
    int e = blockIdx.x * 256 + threadIdx.x;           // 1250*256 == N_EDGES
    atomicAdd(&deg[ei[N_EDGES + e]], 1);
}

// ---------------------------------------------------------------------------
// Fused mid pass (all independent of each other; deg is complete):
//   blocks [0,2048)        : x fp32 -> xb bf16 (streaming)
//   blocks [2048,3072)     : weight fold -> wbT (streaming, 128 active thr)
//   block  3072            : vectorized deg scan -> off, cursor
#define CONV_BLOCKS 2048
#define PREP_BLOCKS 1024

__global__ __launch_bounds__(256) void mid_pass(
        const float* __restrict__ x, short* __restrict__ xb,
        const float* __restrict__ Wsrc, const float* __restrict__ Wdst,
        const float* __restrict__ att_src, const float* __restrict__ att_dst,
        short* __restrict__ wbT,
        const int* __restrict__ deg, int* __restrict__ off,
        int* __restrict__ cursor) {
    int t   = threadIdx.x;
    int bid = blockIdx.x;

    if (bid < CONV_BLOCKS) {               // ---- convert x
        const int total = N_NODES * IN_DIM / 8;
        int stride = CONV_BLOCKS * 256;
        for (int i = bid * 256 + t; i < total; i += stride) {
            float4 a = ((const float4*)x)[(size_t)i * 2];
            float4 b = ((const float4*)x)[(size_t)i * 2 + 1];
            uint4 r;
            r.x = (unsigned int)f2bf(a.x) | ((unsigned int)f2bf(a.y) << 16);
            r.y = (unsigned int)f2bf(a.z) | ((unsigned int)f2bf(a.w) << 16);
            r.z = (unsigned int)f2bf(b.x) | ((unsigned int)f2bf(b.y) << 16);
            r.w = (unsigned int)f2bf(b.z) | ((unsigned int)f2bf(b.w) << 16);
            *(uint4*)(&xb[(size_t)i * 8]) = r;
        }
        return;
    }

    if (bid < CONV_BLOCKS + PREP_BLOCKS) { // ---- weight fold (128 threads used)
        if (t >= 128) return;
        int k = bid - CONV_BLOCKS;
        float4 v = *(const float4*)(Wsrc + (size_t)k * HC + t * 4);
        wbT[(size_t)(t * 4 + 0) * IN_DIM + k] = (short)f2bf(v.x);
        wbT[(size_t)(t * 4 + 1) * IN_DIM + k] = (short)f2bf(v.y);
        wbT[(size_t)(t * 4 + 2) * IN_DIM + k] = (short)f2bf(v.z);
        wbT[(size_t)(t * 4 + 3) * IN_DIM + k] = (short)f2bf(v.w);
        if (t < 16) {
            int h = t & 7;
            const float* W   = (t < 8) ? Wsrc : Wdst;
            const float* att = (t < 8) ? att_src : att_dst;
            float s = 0.f;
            #pragma unroll
            for (int c = 0; c < C_CH; ++c)
                s += W[(size_t)k * HC + h * C_CH + c] * att[h * C_CH + c];
            wbT[(size_t)(512 + t) * IN_DIM + k] = (short)f2bf(s);
        } else if (t < 64) {
            wbT[(size_t)(512 + t) * IN_DIM + k] = 0;   // pad cols 528..575
        }
        return;
    }

    // ---- scan tail block (needs deg, complete from previous launch)
    if (t >= 128) return;
    __shared__ int wtot[2];
    int lane = t & 63, w = t >> 6;
    const int4* deg4 = (const int4*)deg;
    int s = 0;
    if (t < 125) {                         // 125*160 == N_NODES exactly
        #pragma unroll
        for (int j = 0; j < 40; ++j) {
            int4 u = deg4[t * 40 + j];
            s += u.x + u.y + u.z + u.w;
        }
    }
    int v = s;
    #pragma unroll
    for (int o = 1; o < 64; o <<= 1) {
        int u = __shfl_up(v, o);
        if (lane >= o) v += u;
    }
    if (lane == 63) wtot[w] = v;
    __syncthreads();
    int add = (w == 1) ? wtot[0] : 0;
    int run = add + v - s;
    if (t < 125) {
        int4* off4 = (int4*)off;
        int4* cur4 = (int4*)cursor;
        #pragma unroll
        for (int j = 0; j < 40; ++j) {
            int4 u = deg4[t * 40 + j];
            int4 o_;
            o_.x = run;
            o_.y = o_.x + u.x;
            o_.z = o_.y + u.y;
            o_.w = o_.z + u.z;
            off4[t * 40 + j] = o_;
            cur4[t * 40 + j] = o_;
            run = o_.w + u.w;
        }
        if (t == 124) off[N_NODES] = run;
    }
}

// ---------------------------------------------------------------------------
// MFMA GEMM (R12/R19 verbatim — best-measured): small-tile high-TLP
// BM=64 x BN=96 x BK=64, 4 waves (2x2), single 20 KB LDS buffer, coalesced
// staging + XOR swizzle, 1878 GEMM blocks + 1250 fused CSR-scatter blocks.
#define BM 64
#define BN 96
#define BK 64
#define NCOLT (BCOLS / BN)                  // 6
#define NROWT ((N_NODES + BM - 1) / BM)     // 313
#define NWG (NCOLT * NROWT)                 // 1878
#define KSTEPS (IN_DIM / BK)                // 16
#define A_SLOTS (BM * BK / 8)               // 512 x 16B = 8 KB
#define B_SLOTS (BN * BK / 8)               // 768 x 16B = 12 KB

__global__ __launch_bounds__(256) void gemm_scatter(
        const short* __restrict__ xb,
        const short* __restrict__ wbT,
        short* __restrict__ xsb,
        float* __restrict__ a_srcv,
        float* __restrict__ a_dstv,
        const int* __restrict__ ei,
        int* __restrict__ cursor,
        int* __restrict__ csr_src) {
    __shared__ short As[A_SLOTS * 8];       // 8 KB
    __shared__ short Bs[B_SLOTS * 8];       // 12 KB  (20 KB total)

    int t = threadIdx.x;

    // ---- scatter blocks: bare CSR scatter, sorted by dst
    if (blockIdx.x >= NWG) {
        int e = (blockIdx.x - NWG) * 256 + t;   // 1250*256 == N_EDGES exactly
        int d = ei[N_EDGES + e];
        int idx = atomicAdd(&cursor[d], 1);
        csr_src[idx] = ei[e];
        return;
    }

    // bijective XCD swizzle (m204): contiguous chunk of wgids per XCD
    int orig = blockIdx.x;
    const int q = NWG >> 3, r = NWG & 7;
    int xcd  = orig & 7;
    int wgid = (xcd < r ? xcd * (q + 1) : r * (q + 1) + (xcd - r) * q) + (orig >> 3);
    int col0 = (wgid % NCOLT) * BN;         // col tiles fastest -> A rows L2-local
    int row0 = (wgid / NCOLT) * BM;

    int lane = t & 63;
    int w    = t >> 6;
    int lr   = lane & 15;
    int lg   = lane >> 4;                   // k-group 0..3
    int sw   = lr & 7;                      // fragment-read swizzle key
    int wr   = (w >> 1) * 32;               // wave row offset (2x2 waves)
    int wc   = (w & 1) * 48;                // wave col offset

    // staging source pointers: A 2 slots/thread, B 3 slots/thread.
    // slot s: m = s>>3, kcp = s&7; source k-chunk kc = kcp ^ (m&7).
    const short* a_base[2];
    #pragma unroll
    for (int i = 0; i < 2; ++i) {
        int s  = t + 256 * i;               // 0..511
        int m  = s >> 3;
        int kc = (s & 7) ^ (m & 7);
        int gm = row0 + m;
        if (gm >= N_NODES) gm = N_NODES - 1;   // clamp (dead rows, in-bounds)
        a_base[i] = xb + (size_t)gm * IN_DIM + kc * 8;
    }
    const short* b_base[3];
    #pragma unroll
    for (int i = 0; i < 3; ++i) {
        int s  = t + 256 * i;               // 0..767
        int c  = s >> 3;
        int kc = (s & 7) ^ (c & 7);
        b_base[i] = wbT + (size_t)(col0 + c) * IN_DIM + kc * 8;
    }

    f32x4 acc[2][3] = {};

    for (int step = 0; step < KSTEPS; ++step) {
        int k0 = step * BK;
        #pragma unroll
        for (int i = 0; i < 2; ++i)
            gload_lds16(a_base[i] + k0, &As[(t + 256 * i) * 8]);
        #pragma unroll
        for (int i = 0; i < 3; ++i)
            gload_lds16(b_base[i] + k0, &Bs[(t + 256 * i) * 8]);
        asm volatile("s_waitcnt vmcnt(0)" ::: "memory");
        __builtin_amdgcn_s_barrier();

        #pragma unroll
        for (int ks = 0; ks < 2; ++ks) {
            int kc  = ks * 4 + lg;
            int kca = kc ^ sw;              // swizzled chunk index
            bf16x8 af[2], bfr[3];
            #pragma unroll
            for (int mi = 0; mi < 2; ++mi)
                af[mi] = *(const bf16x8*)(&As[((wr + mi * 16 + lr) * 8 + kca) * 8]);
            #pragma unroll
            for (int ni = 0; ni < 3; ++ni)
                bfr[ni] = *(const bf16x8*)(&Bs[((wc + ni * 16 + lr) * 8 + kca) * 8]);
            __builtin_amdgcn_s_setprio(1);
            #pragma unroll
            for (int mi = 0; mi < 2; ++mi)
                #pragma unroll
                for (int ni = 0; ni < 3; ++ni)
                    acc[mi][ni] = __builtin_amdgcn_mfma_f32_16x16x32_bf16(
                        af[mi], bfr[ni], acc[mi][ni], 0, 0, 0);
            __builtin_amdgcn_s_setprio(0);
        }
        __builtin_amdgcn_s_barrier();       // reads done before next overwrite
    }

    // epilogue: C/D layout col=lane&15, row=(lane>>4)*4+reg
    #pragma unroll
    for (int mi = 0; mi < 2; ++mi) {
        #pragma unroll
        for (int rr = 0; rr < 4; ++rr) {
            int row = row0 + wr + mi * 16 + lg * 4 + rr;
            if (row >= N_NODES) continue;
            #pragma unroll
            for (int ni = 0; ni < 3; ++ni) {
                int col = col0 + wc + ni * 16 + lr;
                float v = acc[mi][ni][rr];
                if (col < 512)      xsb[(size_t)row * HC + col] = (short)f2bf(v);
                else if (col < 520) a_srcv[(size_t)row * 8 + (col - 512)] = v;
                else if (col < 528) a_dstv[(size_t)row * 8 + (col - 520)] = v;
            }
        }
    }
}

// ---------------------------------------------------------------------------
// ONE WAVE per destination node (4 independent waves/block, no barriers).
// Unrolled x4 for memory-level parallelism (4 outstanding 1KB gathers/wave).
__global__ __launch_bounds__(256) void aggregate_ln(
        const int* __restrict__ off,
        const int* __restrict__ csr_src,
        const float* __restrict__ a_srcv,
        const float* __restrict__ a_dstv,
        const short* __restrict__ xsb,
        const float* __restrict__ bias,
        const float* __restrict__ gamma,
        const float* __restrict__ beta,
        const float* __restrict__ prelu_a,
        float* __restrict__ out) {
    int lane = threadIdx.x & 63;
    int n    = blockIdx.x * 4 + (threadIdx.x >> 6);   // 5000 x 4 waves = 20000
    int ch0  = lane * 8;
    int h    = lane >> 3;

    int start = off[n], end = off[n + 1];
    float ad  = a_dstv[(size_t)n * 8 + h];

    float acc[8] = {};
    float wsum = 0.f;

#define EDGE_ACC(sv)                                                          \
    do {                                                                      \
        float sc_ = a_srcv[(size_t)(sv) * 8 + h] + ad;                        \
        uint4 u_  = *(const uint4*)(xsb + (size_t)(sv) * HC + ch0);           \
        sc_ = (sc_ >= 0.f) ? sc_ : LEAKY * sc_;                               \
        float w_ = __expf(sc_);                                               \
        acc[0] = fmaf(w_, bf2f(u_.x & 0xffffu), acc[0]);                      \
        acc[1] = fmaf(w_, bf2f(u_.x >> 16),     acc[1]);                      \
        acc[2] = fmaf(w_, bf2f(u_.y & 0xffffu), acc[2]);                      \
        acc[3] = fmaf(w_, bf2f(u_.y >> 16),     acc[3]);                      \
        acc[4] = fmaf(w_, bf2f(u_.z & 0xffffu), acc[4]);                      \
        acc[5] = fmaf(w_, bf2f(u_.z >> 16),     acc[5]);                      \
        acc[6] = fmaf(w_, bf2f(u_.w & 0xffffu), acc[6]);                      \
        acc[7] = fmaf(w_, bf2f(u_.w >> 16),     acc[7]);                      \
        wsum += w_;                                                           \
    } while (0)

    int i = start;
    for (; i + 3 < end; i += 4) {
        int s0 = __builtin_amdgcn_readfirstlane(csr_src[i]);
        int s1 = __builtin_amdgcn_readfirstlane(csr_src[i + 1]);
        int s2 = __builtin_amdgcn_readfirstlane(csr_src[i + 2]);
        int s3 = __builtin_amdgcn_readfirstlane(csr_src[i + 3]);
        EDGE_ACC(s0); EDGE_ACC(s1); EDGE_ACC(s2); EDGE_ACC(s3);
    }
    for (; i < end; ++i) {
        int s0 = __builtin_amdgcn_readfirstlane(csr_src[i]);
        EDGE_ACC(s0);
    }
#undef EDGE_ACC

    float inv = 1.f / (wsum + 1e-16f);
    float4 b0 = *(const float4*)(bias + ch0);
    float4 b1 = *(const float4*)(bias + ch0 + 4);
    float v8[8];
    float psum = 0.f, psq = 0.f;
    const float bb[8] = {b0.x, b0.y, b0.z, b0.w, b1.x, b1.y, b1.z, b1.w};
    #pragma unroll
    for (int j = 0; j < 8; ++j) {
        v8[j] = acc[j] * inv + bb[j];
        psum += v8[j];
        psq  += v8[j] * v8[j];
    }
    #pragma unroll
    for (int o = 32; o > 0; o >>= 1) {
        psum += __shfl_xor(psum, o);
        psq  += __shfl_xor(psq, o);
    }
    float mu   = psum * (1.f / (float)HC);
    float var  = psq * (1.f / (float)HC) - mu * mu;
    float rstd = rsqrtf(var + LN_EPS);

    float4 g0 = *(const float4*)(gamma + ch0);
    float4 g1 = *(const float4*)(gamma + ch0 + 4);
    float4 e0 = *(const float4*)(beta + ch0);
    float4 e1 = *(const float4*)(beta + ch0 + 4);
    float4 p0 = *(const float4*)(prelu_a + ch0);
    float4 p1 = *(const float4*)(prelu_a + ch0 + 4);
    const float gg[8] = {g0.x, g0.y, g0.z, g0.w, g1.x, g1.y, g1.z, g1.w};
    const float ee[8] = {e0.x, e0.y, e0.z, e0.w, e1.x, e1.y, e1.z, e1.w};
    const float pp[8] = {p0.x, p0.y, p0.z, p0.w, p1.x, p1.y, p1.z, p1.w};
    float y[8];
    #pragma unroll
    for (int j = 0; j < 8; ++j) {
        float v = (v8[j] - mu) * rstd * gg[j] + ee[j];
        y[j] = (v >= 0.f) ? v : pp[j] * v;
    }
    float4* o4 = (float4*)(out + (size_t)n * HC + ch0);
    o4[0] = make_float4(y[0], y[1], y[2], y[3]);
    o4[1] = make_float4(y[4], y[5], y[6], y[7]);
}

// ---------------------------------------------------------------------------
extern "C" void kernel_launch(void* const* d_in, const int* in_sizes, int n_in,
                              void* d_out, int out_size, void* d_ws, size_t ws_size,
                              hipStream_t stream) {
    const float* x        = (const float*)d_in[0];
    const int*   ei       = (const int*)d_in[2];
    const float* Wsrc     = (const float*)d_in[4];
    const float* Wdst     = (const float*)d_in[5];
    const float* att_src  = (const float*)d_in[6];
    const float* att_dst  = (const float*)d_in[7];
    const float* bias     = (const float*)d_in[8];
    const float* gamma    = (const float*)d_in[9];
    const float* beta     = (const float*)d_in[10];
    const float* prelu_a  = (const float*)d_in[11];
    float* out            = (float*)d_out;

    char*  ws = (char*)d_ws;
    size_t o  = 0;
    auto alloc = [&](size_t bytes) -> void* {
        void* p = ws + o;
        o += (bytes + 255) & ~(size_t)255;
        return p;
    };
    short* wbT     = (short*)alloc(sizeof(short) * BCOLS * IN_DIM);        // 1.18 MB
    short* xsb     = (short*)alloc(sizeof(short) * (size_t)N_NODES * HC);  // 20.5 MB
    float* a_srcv  = (float*)alloc(sizeof(float) * N_NODES * 8);
    float* a_dstv  = (float*)alloc(sizeof(float) * N_NODES * 8);
    int*   deg     = (int*)alloc(sizeof(int) * N_NODES);
    int*   off     = (int*)alloc(sizeof(int) * (N_NODES + 1));
    int*   cursor  = (int*)alloc(sizeof(int) * N_NODES);
    int*   csr_src = (int*)alloc(sizeof(int) * N_EDGES);                   // 1.28 MB

    // xb (bf16 x) lives in d_out: exactly N*1024*2B = N*512*4B; d_out is dead
    // until aggregate_ln fully overwrites it.
    short* xb = (short*)d_out;

    hipMemsetAsync(deg, 0, sizeof(int) * N_NODES, stream);

    deg_hist<<<DEG_BLOCKS, 256, 0, stream>>>(ei, deg);

    // convert + weight prep + scan fused (all independent; deg complete)
    mid_pass<<<CONV_BLOCKS + PREP_BLOCKS + 1, 256, 0, stream>>>(
        x, xb, Wsrc, Wdst, att_src, att_dst, wbT, deg, off, cursor);

    // GEMM blocks + fused edge_scatter blocks (scatter needs cursor from scan)
    gemm_scatter<<<NWG + DEG_BLOCKS, 256, 0, stream>>>(
        xb, wbT, xsb, a_srcv, a_dstv, ei, cursor, csr_src);

    aggregate_ln<<<N_NODES / 4, 256, 0, stream>>>(
        off, csr_src, a_srcv, a_dstv, xsb, bias, gamma, beta, prelu_a, out);
}

// Round 21
// 151.489 us; speedup vs baseline: 1.3140x; 1.0091x over previous
//
#include <hip/hip_runtime.h>
#include <hip/hip_bf16.h>

#define N_NODES 20000
#define N_EDGES 320000
#define IN_DIM  1024
#define H_HEADS 8
#define C_CH    64
#define HC      512
#define LEAKY   0.2f
#define LN_EPS  1e-5f

// Extended (transposed) weight: rows 0..511 = W_src cols, 512..519 = att_src fold,
// 520..527 = att_dst fold, 528..575 zero pad.  wbT[col][k], bf16.
#define BCOLS 576

typedef short bf16x8 __attribute__((ext_vector_type(8)));
typedef float f32x4  __attribute__((ext_vector_type(4)));

__device__ __forceinline__ unsigned short f2bf(float f) {
    union { float f; unsigned int u; } c; c.f = f;
    unsigned int u = c.u;
    unsigned int r = (u + 0x7fffu + ((u >> 16) & 1u)) >> 16;   // RNE
    return (unsigned short)r;
}
__device__ __forceinline__ float bf2f(unsigned int h) {
    union { unsigned int u; float f; } c; c.u = h << 16; return c.f;
}
// HW packed f32->bf16 (RNE), 1 instr per 2 elements
__device__ __forceinline__ unsigned int cvtpk(float lo, float hi) {
    unsigned int r;
    asm("v_cvt_pk_bf16_f32 %0, %1, %2" : "=v"(r) : "v"(lo), "v"(hi));
    return r;
}
__device__ __forceinline__ void gload_lds16(const void* g, void* l) {
    __builtin_amdgcn_global_load_lds(
        (const __attribute__((address_space(1))) unsigned int*)g,
        (__attribute__((address_space(3))) unsigned int*)l, 16, 0, 0);
}

// ---------------------------------------------------------------------------
#define DEG_BLOCKS 1250

__global__ __launch_bounds__(256) void deg_hist(
        const int* __restrict__ ei, int* __restrict__ deg) {
    int e = blockIdx.x * 256 + threadIdx.x;           // 1250*256 == N_EDGES
    atomicAdd(&deg[ei[N_EDGES + e]], 1);
}

// ---------------------------------------------------------------------------
// Fused mid pass (all independent of each other; deg is complete):
//   blocks [0,2500)        : x fp32 -> xb bf16.  4-way MLP: each thread owns
//                            exactly 4 items (8-elem chunks) at 640K stride;
//                            all 8 float4 loads issued straight-line BEFORE
//                            any convert/store (old grid-stride loop was
//                            latency-serial: 1 load pair in flight -> 55 us).
//   blocks [2500,3524)     : weight fold -> wbT (128 active threads)
//   block  3524            : vectorized deg scan -> off, cursor
#define CONV_BLOCKS 2500
#define CONV_STRIDE 640000                  // items; 4*640000 == 2,560,000
#define PREP_BLOCKS 1024

__global__ __launch_bounds__(256) void mid_pass(
        const float* __restrict__ x, short* __restrict__ xb,
        const float* __restrict__ Wsrc, const float* __restrict__ Wdst,
        const float* __restrict__ att_src, const float* __restrict__ att_dst,
        short* __restrict__ wbT,
        const int* __restrict__ deg, int* __restrict__ off,
        int* __restrict__ cursor) {
    int t   = threadIdx.x;
    int bid = blockIdx.x;

    if (bid < CONV_BLOCKS) {               // ---- convert x (4-way MLP)
        int i0 = bid * 256 + t;            // 0..639,999
        const float4* x4 = (const float4*)x;
        float4 a0 = x4[(size_t)(i0                  ) * 2];
        float4 b0 = x4[(size_t)(i0                  ) * 2 + 1];
        float4 a1 = x4[(size_t)(i0 + CONV_STRIDE    ) * 2];
        float4 b1 = x4[(size_t)(i0 + CONV_STRIDE    ) * 2 + 1];
        float4 a2 = x4[(size_t)(i0 + CONV_STRIDE * 2) * 2];
        float4 b2 = x4[(size_t)(i0 + CONV_STRIDE * 2) * 2 + 1];
        float4 a3 = x4[(size_t)(i0 + CONV_STRIDE * 3) * 2];
        float4 b3 = x4[(size_t)(i0 + CONV_STRIDE * 3) * 2 + 1];
        uint4 r0, r1, r2, r3;
        r0.x = cvtpk(a0.x, a0.y);  r0.y = cvtpk(a0.z, a0.w);
        r0.z = cvtpk(b0.x, b0.y);  r0.w = cvtpk(b0.z, b0.w);
        r1.x = cvtpk(a1.x, a1.y);  r1.y = cvtpk(a1.z, a1.w);
        r1.z = cvtpk(b1.x, b1.y);  r1.w = cvtpk(b1.z, b1.w);
        r2.x = cvtpk(a2.x, a2.y);  r2.y = cvtpk(a2.z, a2.w);
        r2.z = cvtpk(b2.x, b2.y);  r2.w = cvtpk(b2.z, b2.w);
        r3.x = cvtpk(a3.x, a3.y);  r3.y = cvtpk(a3.z, a3.w);
        r3.z = cvtpk(b3.x, b3.y);  r3.w = cvtpk(b3.z, b3.w);
        *(uint4*)(&xb[(size_t)(i0                  ) * 8]) = r0;
        *(uint4*)(&xb[(size_t)(i0 + CONV_STRIDE    ) * 8]) = r1;
        *(uint4*)(&xb[(size_t)(i0 + CONV_STRIDE * 2) * 8]) = r2;
        *(uint4*)(&xb[(size_t)(i0 + CONV_STRIDE * 3) * 8]) = r3;
        return;
    }

    if (bid < CONV_BLOCKS + PREP_BLOCKS) { // ---- weight fold (128 threads used)
        if (t >= 128) return;
        int k = bid - CONV_BLOCKS;
        float4 v = *(const float4*)(Wsrc + (size_t)k * HC + t * 4);
        wbT[(size_t)(t * 4 + 0) * IN_DIM + k] = (short)f2bf(v.x);
        wbT[(size_t)(t * 4 + 1) * IN_DIM + k] = (short)f2bf(v.y);
        wbT[(size_t)(t * 4 + 2) * IN_DIM + k] = (short)f2bf(v.z);
        wbT[(size_t)(t * 4 + 3) * IN_DIM + k] = (short)f2bf(v.w);
        if (t < 16) {
            int h = t & 7;
            const float* W   = (t < 8) ? Wsrc : Wdst;
            const float* att = (t < 8) ? att_src : att_dst;
            float s = 0.f;
            #pragma unroll
            for (int c = 0; c < C_CH; ++c)
                s += W[(size_t)k * HC + h * C_CH + c] * att[h * C_CH + c];
            wbT[(size_t)(512 + t) * IN_DIM + k] = (short)f2bf(s);
        } else if (t < 64) {
            wbT[(size_t)(512 + t) * IN_DIM + k] = 0;   // pad cols 528..575
        }
        return;
    }

    // ---- scan tail block (needs deg, complete from previous launch)
    if (t >= 128) return;
    __shared__ int wtot[2];
    int lane = t & 63, w = t >> 6;
    const int4* deg4 = (const int4*)deg;
    int s = 0;
    if (t < 125) {                         // 125*160 == N_NODES exactly
        #pragma unroll
        for (int j = 0; j < 40; ++j) {
            int4 u = deg4[t * 40 + j];
            s += u.x + u.y + u.z + u.w;
        }
    }
    int v = s;
    #pragma unroll
    for (int o = 1; o < 64; o <<= 1) {
        int u = __shfl_up(v, o);
        if (lane >= o) v += u;
    }
    if (lane == 63) wtot[w] = v;
    __syncthreads();
    int add = (w == 1) ? wtot[0] : 0;
    int run = add + v - s;
    if (t < 125) {
        int4* off4 = (int4*)off;
        int4* cur4 = (int4*)cursor;
        #pragma unroll
        for (int j = 0; j < 40; ++j) {
            int4 u = deg4[t * 40 + j];
            int4 o_;
            o_.x = run;
            o_.y = o_.x + u.x;
            o_.z = o_.y + u.y;
            o_.w = o_.z + u.z;
            off4[t * 40 + j] = o_;
            cur4[t * 40 + j] = o_;
            run = o_.w + u.w;
        }
        if (t == 124) off[N_NODES] = run;
    }
}

// ---------------------------------------------------------------------------
// MFMA GEMM (R12/R19 verbatim — best-measured): small-tile high-TLP
// BM=64 x BN=96 x BK=64, 4 waves (2x2), single 20 KB LDS buffer, coalesced
// staging + XOR swizzle, 1878 GEMM blocks + 1250 fused CSR-scatter blocks.
#define BM 64
#define BN 96
#define BK 64
#define NCOLT (BCOLS / BN)                  // 6
#define NROWT ((N_NODES + BM - 1) / BM)     // 313
#define NWG (NCOLT * NROWT)                 // 1878
#define KSTEPS (IN_DIM / BK)                // 16
#define A_SLOTS (BM * BK / 8)               // 512 x 16B = 8 KB
#define B_SLOTS (BN * BK / 8)               // 768 x 16B = 12 KB

__global__ __launch_bounds__(256) void gemm_scatter(
        const short* __restrict__ xb,
        const short* __restrict__ wbT,
        short* __restrict__ xsb,
        float* __restrict__ a_srcv,
        float* __restrict__ a_dstv,
        const int* __restrict__ ei,
        int* __restrict__ cursor,
        int* __restrict__ csr_src) {
    __shared__ short As[A_SLOTS * 8];       // 8 KB
    __shared__ short Bs[B_SLOTS * 8];       // 12 KB  (20 KB total)

    int t = threadIdx.x;

    // ---- scatter blocks: bare CSR scatter, sorted by dst
    if (blockIdx.x >= NWG) {
        int e = (blockIdx.x - NWG) * 256 + t;   // 1250*256 == N_EDGES exactly
        int d = ei[N_EDGES + e];
        int idx = atomicAdd(&cursor[d], 1);
        csr_src[idx] = ei[e];
        return;
    }

    // bijective XCD swizzle (m204): contiguous chunk of wgids per XCD
    int orig = blockIdx.x;
    const int q = NWG >> 3, r = NWG & 7;
    int xcd  = orig & 7;
    int wgid = (xcd < r ? xcd * (q + 1) : r * (q + 1) + (xcd - r) * q) + (orig >> 3);
    int col0 = (wgid % NCOLT) * BN;         // col tiles fastest -> A rows L2-local
    int row0 = (wgid / NCOLT) * BM;

    int lane = t & 63;
    int w    = t >> 6;
    int lr   = lane & 15;
    int lg   = lane >> 4;                   // k-group 0..3
    int sw   = lr & 7;                      // fragment-read swizzle key
    int wr   = (w >> 1) * 32;               // wave row offset (2x2 waves)
    int wc   = (w & 1) * 48;                // wave col offset

    // staging source pointers: A 2 slots/thread, B 3 slots/thread.
    // slot s: m = s>>3, kcp = s&7; source k-chunk kc = kcp ^ (m&7).
    const short* a_base[2];
    #pragma unroll
    for (int i = 0; i < 2; ++i) {
        int s  = t + 256 * i;               // 0..511
        int m  = s >> 3;
        int kc = (s & 7) ^ (m & 7);
        int gm = row0 + m;
        if (gm >= N_NODES) gm = N_NODES - 1;   // clamp (dead rows, in-bounds)
        a_base[i] = xb + (size_t)gm * IN_DIM + kc * 8;
    }
    const short* b_base[3];
    #pragma unroll
    for (int i = 0; i < 3; ++i) {
        int s  = t + 256 * i;               // 0..767
        int c  = s >> 3;
        int kc = (s & 7) ^ (c & 7);
        b_base[i] = wbT + (size_t)(col0 + c) * IN_DIM + kc * 8;
    }

    f32x4 acc[2][3] = {};

    for (int step = 0; step < KSTEPS; ++step) {
        int k0 = step * BK;
        #pragma unroll
        for (int i = 0; i < 2; ++i)
            gload_lds16(a_base[i] + k0, &As[(t + 256 * i) * 8]);
        #pragma unroll
        for (int i = 0; i < 3; ++i)
            gload_lds16(b_base[i] + k0, &Bs[(t + 256 * i) * 8]);
        asm volatile("s_waitcnt vmcnt(0)" ::: "memory");
        __builtin_amdgcn_s_barrier();

        #pragma unroll
        for (int ks = 0; ks < 2; ++ks) {
            int kc  = ks * 4 + lg;
            int kca = kc ^ sw;              // swizzled chunk index
            bf16x8 af[2], bfr[3];
            #pragma unroll
            for (int mi = 0; mi < 2; ++mi)
                af[mi] = *(const bf16x8*)(&As[((wr + mi * 16 + lr) * 8 + kca) * 8]);
            #pragma unroll
            for (int ni = 0; ni < 3; ++ni)
                bfr[ni] = *(const bf16x8*)(&Bs[((wc + ni * 16 + lr) * 8 + kca) * 8]);
            __builtin_amdgcn_s_setprio(1);
            #pragma unroll
            for (int mi = 0; mi < 2; ++mi)
                #pragma unroll
                for (int ni = 0; ni < 3; ++ni)
                    acc[mi][ni] = __builtin_amdgcn_mfma_f32_16x16x32_bf16(
                        af[mi], bfr[ni], acc[mi][ni], 0, 0, 0);
            __builtin_amdgcn_s_setprio(0);
        }
        __builtin_amdgcn_s_barrier();       // reads done before next overwrite
    }

    // epilogue: C/D layout col=lane&15, row=(lane>>4)*4+reg
    #pragma unroll
    for (int mi = 0; mi < 2; ++mi) {
        #pragma unroll
        for (int rr = 0; rr < 4; ++rr) {
            int row = row0 + wr + mi * 16 + lg * 4 + rr;
            if (row >= N_NODES) continue;
            #pragma unroll
            for (int ni = 0; ni < 3; ++ni) {
                int col = col0 + wc + ni * 16 + lr;
                float v = acc[mi][ni][rr];
                if (col < 512)      xsb[(size_t)row * HC + col] = (short)f2bf(v);
                else if (col < 520) a_srcv[(size_t)row * 8 + (col - 512)] = v;
                else if (col < 528) a_dstv[(size_t)row * 8 + (col - 520)] = v;
            }
        }
    }
}

// ---------------------------------------------------------------------------
// ONE WAVE per destination node (4 independent waves/block, no barriers).
// Unrolled x4 for memory-level parallelism (4 outstanding 1KB gathers/wave).
__global__ __launch_bounds__(256) void aggregate_ln(
        const int* __restrict__ off,
        const int* __restrict__ csr_src,
        const float* __restrict__ a_srcv,
        const float* __restrict__ a_dstv,
        const short* __restrict__ xsb,
        const float* __restrict__ bias,
        const float* __restrict__ gamma,
        const float* __restrict__ beta,
        const float* __restrict__ prelu_a,
        float* __restrict__ out) {
    int lane = threadIdx.x & 63;
    int n    = blockIdx.x * 4 + (threadIdx.x >> 6);   // 5000 x 4 waves = 20000
    int ch0  = lane * 8;
    int h    = lane >> 3;

    int start = off[n], end = off[n + 1];
    float ad  = a_dstv[(size_t)n * 8 + h];

    float acc[8] = {};
    float wsum = 0.f;

#define EDGE_ACC(sv)                                                          \
    do {                                                                      \
        float sc_ = a_srcv[(size_t)(sv) * 8 + h] + ad;                        \
        uint4 u_  = *(const uint4*)(xsb + (size_t)(sv) * HC + ch0);           \
        sc_ = (sc_ >= 0.f) ? sc_ : LEAKY * sc_;                               \
        float w_ = __expf(sc_);                                               \
        acc[0] = fmaf(w_, bf2f(u_.x & 0xffffu), acc[0]);                      \
        acc[1] = fmaf(w_, bf2f(u_.x >> 16),     acc[1]);                      \
        acc[2] = fmaf(w_, bf2f(u_.y & 0xffffu), acc[2]);                      \
        acc[3] = fmaf(w_, bf2f(u_.y >> 16),     acc[3]);                      \
        acc[4] = fmaf(w_, bf2f(u_.z & 0xffffu), acc[4]);                      \
        acc[5] = fmaf(w_, bf2f(u_.z >> 16),     acc[5]);                      \
        acc[6] = fmaf(w_, bf2f(u_.w & 0xffffu), acc[6]);                      \
        acc[7] = fmaf(w_, bf2f(u_.w >> 16),     acc[7]);                      \
        wsum += w_;                                                           \
    } while (0)

    int i = start;
    for (; i + 3 < end; i += 4) {
        int s0 = __builtin_amdgcn_readfirstlane(csr_src[i]);
        int s1 = __builtin_amdgcn_readfirstlane(csr_src[i + 1]);
        int s2 = __builtin_amdgcn_readfirstlane(csr_src[i + 2]);
        int s3 = __builtin_amdgcn_readfirstlane(csr_src[i + 3]);
        EDGE_ACC(s0); EDGE_ACC(s1); EDGE_ACC(s2); EDGE_ACC(s3);
    }
    for (; i < end; ++i) {
        int s0 = __builtin_amdgcn_readfirstlane(csr_src[i]);
        EDGE_ACC(s0);
    }
#undef EDGE_ACC

    float inv = 1.f / (wsum + 1e-16f);
    float4 b0 = *(const float4*)(bias + ch0);
    float4 b1 = *(const float4*)(bias + ch0 + 4);
    float v8[8];
    float psum = 0.f, psq = 0.f;
    const float bb[8] = {b0.x, b0.y, b0.z, b0.w, b1.x, b1.y, b1.z, b1.w};
    #pragma unroll
    for (int j = 0; j < 8; ++j) {
        v8[j] = acc[j] * inv + bb[j];
        psum += v8[j];
        psq  += v8[j] * v8[j];
    }
    #pragma unroll
    for (int o = 32; o > 0; o >>= 1) {
        psum += __shfl_xor(psum, o);
        psq  += __shfl_xor(psq, o);
    }
    float mu   = psum * (1.f / (float)HC);
    float var  = psq * (1.f / (float)HC) - mu * mu;
    float rstd = rsqrtf(var + LN_EPS);

    float4 g0 = *(const float4*)(gamma + ch0);
    float4 g1 = *(const float4*)(gamma + ch0 + 4);
    float4 e0 = *(const float4*)(beta + ch0);
    float4 e1 = *(const float4*)(beta + ch0 + 4);
    float4 p0 = *(const float4*)(prelu_a + ch0);
    float4 p1 = *(const float4*)(prelu_a + ch0 + 4);
    const float gg[8] = {g0.x, g0.y, g0.z, g0.w, g1.x, g1.y, g1.z, g1.w};
    const float ee[8] = {e0.x, e0.y, e0.z, e0.w, e1.x, e1.y, e1.z, e1.w};
    const float pp[8] = {p0.x, p0.y, p0.z, p0.w, p1.x, p1.y, p1.z, p1.w};
    float y[8];
    #pragma unroll
    for (int j = 0; j < 8; ++j) {
        float v = (v8[j] - mu) * rstd * gg[j] + ee[j];
        y[j] = (v >= 0.f) ? v : pp[j] * v;
    }
    float4* o4 = (float4*)(out + (size_t)n * HC + ch0);
    o4[0] = make_float4(y[0], y[1], y[2], y[3]);
    o4[1] = make_float4(y[4], y[5], y[6], y[7]);
}

// ---------------------------------------------------------------------------
extern "C" void kernel_launch(void* const* d_in, const int* in_sizes, int n_in,
                              void* d_out, int out_size, void* d_ws, size_t ws_size,
                              hipStream_t stream) {
    const float* x        = (const float*)d_in[0];
    const int*   ei       = (const int*)d_in[2];
    const float* Wsrc     = (const float*)d_in[4];
    const float* Wdst     = (const float*)d_in[5];
    const float* att_src  = (const float*)d_in[6];
    const float* att_dst  = (const float*)d_in[7];
    const float* bias     = (const float*)d_in[8];
    const float* gamma    = (const float*)d_in[9];
    const float* beta     = (const float*)d_in[10];
    const float* prelu_a  = (const float*)d_in[11];
    float* out            = (float*)d_out;

    char*  ws = (char*)d_ws;
    size_t o  = 0;
    auto alloc = [&](size_t bytes) -> void* {
        void* p = ws + o;
        o += (bytes + 255) & ~(size_t)255;
        return p;
    };
    short* wbT     = (short*)alloc(sizeof(short) * BCOLS * IN_DIM);        // 1.18 MB
    short* xsb     = (short*)alloc(sizeof(short) * (size_t)N_NODES * HC);  // 20.5 MB
    float* a_srcv  = (float*)alloc(sizeof(float) * N_NODES * 8);
    float* a_dstv  = (float*)alloc(sizeof(float) * N_NODES * 8);
    int*   deg     = (int*)alloc(sizeof(int) * N_NODES);
    int*   off     = (int*)alloc(sizeof(int) * (N_NODES + 1));
    int*   cursor  = (int*)alloc(sizeof(int) * N_NODES);
    int*   csr_src = (int*)alloc(sizeof(int) * N_EDGES);                   // 1.28 MB

    // xb (bf16 x) lives in d_out: exactly N*1024*2B = N*512*4B; d_out is dead
    // until aggregate_ln fully overwrites it.
    short* xb = (short*)d_out;

    hipMemsetAsync(deg, 0, sizeof(int) * N_NODES, stream);

    deg_hist<<<DEG_BLOCKS, 256, 0, stream>>>(ei, deg);

    // convert + weight prep + scan fused (all independent; deg complete)
    mid_pass<<<CONV_BLOCKS + PREP_BLOCKS + 1, 256, 0, stream>>>(
        x, xb, Wsrc, Wdst, att_src, att_dst, wbT, deg, off, cursor);

    // GEMM blocks + fused edge_scatter blocks (scatter needs cursor from scan)
    gemm_scatter<<<NWG + DEG_BLOCKS, 256, 0, stream>>>(
        xb, wbT, xsb, a_srcv, a_dstv, ei, cursor, csr_src);

    aggregate_ln<<<N_NODES / 4, 256, 0, stream>>>(
        off, csr_src, a_srcv, a_dstv, xsb, bias, gamma, beta, prelu_a, out);
}